// Round 1
// baseline (308.237 us; speedup 1.0000x reference)
//
#include <hip/hip_runtime.h>
#include <stdint.h>

#define B_   8
#define N_   2048
#define F_   256
#define BN_  (B_ * N_)
#define ALPHA_ 0.2f

typedef __attribute__((ext_vector_type(8))) short  short8;
typedef __attribute__((ext_vector_type(4))) float  f32x4;

__device__ __forceinline__ unsigned short f2bf(float x) {
  uint32_t u = __float_as_uint(x);
  uint32_t r = (u + 0x7fffu + ((u >> 16) & 1u)) >> 16;  // RNE
  return (unsigned short)r;
}

__device__ __forceinline__ void async_load16(const void* g, void* l) {
  __builtin_amdgcn_global_load_lds(
      (const __attribute__((address_space(1))) uint32_t*)g,
      (__attribute__((address_space(3))) uint32_t*)l, 16, 0, 0);
}

// ---------------- conversion kernels ----------------
__global__ void k_cvt_inp(const float* __restrict__ x, unsigned short* __restrict__ y) {
  int idx = (blockIdx.x * 256 + threadIdx.x) * 4;
  float4 v = *(const float4*)(x + idx);
  ushort4 p;
  p.x = f2bf(v.x); p.y = f2bf(v.y); p.z = f2bf(v.z); p.w = f2bf(v.w);
  *(ushort4*)(y + idx) = p;
}

__global__ void k_cvt_w(const float* __restrict__ W, unsigned short* __restrict__ WT) {
  int k = blockIdx.x, n = threadIdx.x;
  WT[n * F_ + k] = f2bf(W[k * F_ + n]);  // WT[f][k], k contiguous (MFMA B layout)
}

// ---------------- GEMM1: h = inp @ W, fused s1/s2, writes hT bf16 ----------------
__launch_bounds__(256, 1)
__global__ void k_gemm1(const unsigned short* __restrict__ inpb,  // [BN][F] bf16
                        const unsigned short* __restrict__ WT,    // [F][F]  bf16 (transposed W)
                        const float* __restrict__ avec,           // [2F]
                        unsigned short* __restrict__ hT,          // [F][BN] bf16
                        float* __restrict__ s1g, float* __restrict__ s2g) {
  __shared__ __align__(16) unsigned short Atile[64 * 32];   // [r][k] r*64B + p*16B
  __shared__ __align__(16) unsigned short Btile[256 * 32];  // [f][k]
  __shared__ float s1_lds[64], s2_lds[64];

  const int tid  = threadIdx.x;
  const int wave = tid >> 6, lane = tid & 63;
  const int n16  = lane & 15, quad = lane >> 4;
  const int i0   = blockIdx.x * 64;

  if (tid < 64) { s1_lds[tid] = 0.0f; s2_lds[tid] = 0.0f; }

  f32x4 acc[4][4];
  #pragma unroll
  for (int mt = 0; mt < 4; ++mt)
    #pragma unroll
    for (int nt = 0; nt < 4; ++nt) acc[mt][nt] = (f32x4){0.f, 0.f, 0.f, 0.f};

  for (int k0 = 0; k0 < F_; k0 += 32) {
    {  // stage A: each wave 1 instr -> its 16 rows
      int r = (wave << 4) + (lane >> 2);
      int p = lane & 3;
      async_load16(inpb + (size_t)(i0 + r) * F_ + k0 + p * 8,
                   (char*)Atile + wave * 1024);
    }
    #pragma unroll
    for (int g4 = 0; g4 < 4; ++g4) {  // stage B: 4 instr/wave -> 64 f-rows
      int f = (wave << 6) + (g4 << 4) + (lane >> 2);
      int p = lane & 3;
      async_load16(WT + (size_t)f * F_ + k0 + p * 8,
                   (char*)Btile + wave * 4096 + g4 * 1024);
    }
    __syncthreads();

    short8 af[4], bf_[4];
    #pragma unroll
    for (int mt = 0; mt < 4; ++mt)
      af[mt] = *(const short8*)((const char*)Atile + ((mt * 16 + n16) * 64 + quad * 16));
    #pragma unroll
    for (int nt = 0; nt < 4; ++nt)
      bf_[nt] = *(const short8*)((const char*)Btile + ((wave * 64 + nt * 16 + n16) * 64 + quad * 16));
    #pragma unroll
    for (int mt = 0; mt < 4; ++mt)
      #pragma unroll
      for (int nt = 0; nt < 4; ++nt)
        acc[mt][nt] = __builtin_amdgcn_mfma_f32_16x16x32_bf16(af[mt], bf_[nt], acc[mt][nt], 0, 0, 0);
    __syncthreads();
  }

  // epilogue: hT store + fused s1/s2
  float a1v[4], a2v[4];
  #pragma unroll
  for (int nt = 0; nt < 4; ++nt) {
    int f = (wave << 6) + (nt << 4) + n16;
    a1v[nt] = avec[f];
    a2v[nt] = avec[F_ + f];
  }
  #pragma unroll
  for (int mt = 0; mt < 4; ++mt) {
    float s1p[4] = {0, 0, 0, 0}, s2p[4] = {0, 0, 0, 0};
    #pragma unroll
    for (int nt = 0; nt < 4; ++nt) {
      int f  = (wave << 6) + (nt << 4) + n16;
      int ig = i0 + (mt << 4) + (quad << 2);
      ushort4 pk;
      pk.x = f2bf(acc[mt][nt][0]); pk.y = f2bf(acc[mt][nt][1]);
      pk.z = f2bf(acc[mt][nt][2]); pk.w = f2bf(acc[mt][nt][3]);
      *(ushort4*)(hT + (size_t)f * BN_ + ig) = pk;
      #pragma unroll
      for (int rg = 0; rg < 4; ++rg) {
        s1p[rg] = fmaf(acc[mt][nt][rg], a1v[nt], s1p[rg]);
        s2p[rg] = fmaf(acc[mt][nt][rg], a2v[nt], s2p[rg]);
      }
    }
    #pragma unroll
    for (int rg = 0; rg < 4; ++rg) {
      float v1 = s1p[rg], v2 = s2p[rg];
      #pragma unroll
      for (int off = 1; off < 16; off <<= 1) {
        v1 += __shfl_xor(v1, off);
        v2 += __shfl_xor(v2, off);
      }
      if (n16 == 0) {
        atomicAdd(&s1_lds[(mt << 4) + (quad << 2) + rg], v1);
        atomicAdd(&s2_lds[(mt << 4) + (quad << 2) + rg], v2);
      }
    }
  }
  __syncthreads();
  if (tid < 64) {
    s1g[i0 + tid] = s1_lds[tid];
    s2g[i0 + tid] = s2_lds[tid];
  }
}

// ---------------- per-batch min/max of s1/s2 -> affine params ----------------
__global__ void k_minmax(const float* __restrict__ s1, const float* __restrict__ s2,
                         float2* __restrict__ params) {
  int b = blockIdx.x, tid = threadIdx.x;
  float mn1 = 1e30f, mx1 = -1e30f, mn2 = 1e30f, mx2 = -1e30f;
  for (int i = tid; i < N_; i += 256) {
    float v1 = s1[b * N_ + i]; mn1 = fminf(mn1, v1); mx1 = fmaxf(mx1, v1);
    float v2 = s2[b * N_ + i]; mn2 = fminf(mn2, v2); mx2 = fmaxf(mx2, v2);
  }
  #pragma unroll
  for (int off = 1; off < 64; off <<= 1) {
    mn1 = fminf(mn1, __shfl_xor(mn1, off));
    mx1 = fmaxf(mx1, __shfl_xor(mx1, off));
    mn2 = fminf(mn2, __shfl_xor(mn2, off));
    mx2 = fmaxf(mx2, __shfl_xor(mx2, off));
  }
  __shared__ float red[4][4];
  int wave = tid >> 6, lane = tid & 63;
  if (lane == 0) { red[wave][0] = mn1; red[wave][1] = mx1; red[wave][2] = mn2; red[wave][3] = mx2; }
  __syncthreads();
  if (tid == 0) {
    for (int w = 1; w < 4; ++w) {
      mn1 = fminf(mn1, red[w][0]); mx1 = fmaxf(mx1, red[w][1]);
      mn2 = fminf(mn2, red[w][2]); mx2 = fmaxf(mx2, red[w][3]);
    }
    // leaky_relu monotone: extremes of e come from extremes of s1+s2
    float smn = mn1 + mn2, smx = mx1 + mx2;
    float mn = fmaxf(smn, ALPHA_ * smn);
    float mx = fmaxf(smx, ALPHA_ * smx);
    float scale = 30.0f / (mx - mn);
    float bias  = -mn * scale - 20.0f;
    params[b] = make_float2(-scale, -bias);  // for u = -e: att = rcp(1+exp(u))
  }
}

// ---------------- GEMM2: attention generated on the fly, h_prime = elu(att @ h) ----------------
__launch_bounds__(256, 1)
__global__ void k_gemm2(const unsigned short* __restrict__ hT,  // [F][BN] bf16
                        const float* __restrict__ s1, const float* __restrict__ s2,
                        const float2* __restrict__ params,
                        float* __restrict__ hprime,  // [B][N][F]
                        float* __restrict__ att) {   // [B][N][N]
  __shared__ __align__(16) unsigned short Atile[64 * 32];   // attention tile [r][k]
  __shared__ __align__(16) unsigned short Btile[256 * 32];  // hT tile [f][k]

  const int tid  = threadIdx.x;
  const int wave = tid >> 6, lane = tid & 63;
  const int n16  = lane & 15, quad = lane >> 4;
  const int blk  = blockIdx.x;
  const int b    = blk & 7;            // batch = blk%8 -> XCD-local hT_b in L2
  const int i0   = (blk >> 3) * 64;    // row tile within batch

  const float2 pb = params[b];
  const float uscale = pb.x, ubias = pb.y;

  const int r_att = tid >> 2;   // 0..63
  const int p_att = tid & 3;    // k-part (8 consecutive j)
  const float s1v = s1[b * N_ + i0 + r_att];
  const float* s2b = s2 + b * N_;
  float* attrow = att + ((size_t)(b * N_ + i0 + r_att)) * N_;

  f32x4 acc[4][4];
  #pragma unroll
  for (int mt = 0; mt < 4; ++mt)
    #pragma unroll
    for (int nt = 0; nt < 4; ++nt) acc[mt][nt] = (f32x4){0.f, 0.f, 0.f, 0.f};

  for (int k0 = 0; k0 < N_; k0 += 32) {
    #pragma unroll
    for (int g4 = 0; g4 < 4; ++g4) {  // stage hT tile (256 f-rows x 32 k)
      int f = (wave << 6) + (g4 << 4) + (lane >> 2);
      int p = lane & 3;
      async_load16(hT + (size_t)f * BN_ + b * N_ + k0 + p * 8,
                   (char*)Btile + wave * 4096 + g4 * 1024);
    }

    // compute 8 attention values (overlaps with async staging)
    float4 va = *(const float4*)(s2b + k0 + p_att * 8);
    float4 vb = *(const float4*)(s2b + k0 + p_att * 8 + 4);
    float v[8] = {va.x, va.y, va.z, va.w, vb.x, vb.y, vb.z, vb.w};
    short8 spk;
    #pragma unroll
    for (int jj = 0; jj < 8; ++jj) {
      float s = s1v + v[jj];
      float l = fmaxf(s, ALPHA_ * s);                       // leaky_relu
      float u = fmaf(l, uscale, ubias);                     // u = -e_norm
      float p_ = __builtin_amdgcn_rcpf(1.0f + __expf(u));   // sigmoid(e_norm)
      v[jj] = p_;
      spk[jj] = (short)f2bf(p_);
    }
    *(float4*)(attrow + k0 + p_att * 8)     = make_float4(v[0], v[1], v[2], v[3]);
    *(float4*)(attrow + k0 + p_att * 8 + 4) = make_float4(v[4], v[5], v[6], v[7]);
    *(short8*)((char*)Atile + tid * 16) = spk;
    __syncthreads();

    short8 af[4], bf_[4];
    #pragma unroll
    for (int mt = 0; mt < 4; ++mt)
      af[mt] = *(const short8*)((const char*)Atile + ((mt * 16 + n16) * 64 + quad * 16));
    #pragma unroll
    for (int nt = 0; nt < 4; ++nt)
      bf_[nt] = *(const short8*)((const char*)Btile + ((wave * 64 + nt * 16 + n16) * 64 + quad * 16));
    #pragma unroll
    for (int mt = 0; mt < 4; ++mt)
      #pragma unroll
      for (int nt = 0; nt < 4; ++nt)
        acc[mt][nt] = __builtin_amdgcn_mfma_f32_16x16x32_bf16(af[mt], bf_[nt], acc[mt][nt], 0, 0, 0);
    __syncthreads();
  }

  // epilogue: ELU + store h_prime
  float* hp = hprime + ((size_t)(b * N_ + i0)) * F_;
  #pragma unroll
  for (int mt = 0; mt < 4; ++mt)
    #pragma unroll
    for (int nt = 0; nt < 4; ++nt) {
      int fcol = (wave << 6) + (nt << 4) + n16;
      int irow = (mt << 4) + (quad << 2);
      #pragma unroll
      for (int rg = 0; rg < 4; ++rg) {
        float x = acc[mt][nt][rg];
        float y = x > 0.0f ? x : (__expf(x) - 1.0f);
        hp[(size_t)(irow + rg) * F_ + fcol] = y;
      }
    }
}

// ---------------- launch ----------------
extern "C" void kernel_launch(void* const* d_in, const int* in_sizes, int n_in,
                              void* d_out, int out_size, void* d_ws, size_t ws_size,
                              hipStream_t stream) {
  const float* inp  = (const float*)d_in[0];
  // d_in[1] = adj: unused by the reference computation
  const float* W    = (const float*)d_in[2];
  const float* avec = (const float*)d_in[3];

  float* hprime = (float*)d_out;                         // [8][2048][256]
  float* att    = (float*)d_out + (size_t)B_ * N_ * F_;  // [8][2048][2048]

  char* ws = (char*)d_ws;
  unsigned short* inpb = (unsigned short*)ws;                          // 8 MB
  unsigned short* WT   = (unsigned short*)(ws + 8388608);              // 128 KB
  unsigned short* hT   = (unsigned short*)(ws + 8388608 + 131072);     // 8 MB
  float* s1            = (float*)(ws + 8388608 + 131072 + 8388608);
  float* s2            = s1 + BN_;
  float2* params       = (float2*)(s2 + BN_);

  k_cvt_inp<<<(BN_ * F_) / 1024, 256, 0, stream>>>(inp, inpb);
  k_cvt_w<<<F_, F_, 0, stream>>>(W, WT);
  k_gemm1<<<BN_ / 64, 256, 0, stream>>>(inpb, WT, avec, hT, s1, s2);
  k_minmax<<<B_, 256, 0, stream>>>(s1, s2, params);
  k_gemm2<<<256, 256, 0, stream>>>(hT, s1, s2, params, hprime, att);
}

// Round 2
// 289.284 us; speedup vs baseline: 1.0655x; 1.0655x over previous
//
#include <hip/hip_runtime.h>
#include <stdint.h>

#define B_   8
#define N_   2048
#define F_   256
#define BN_  (B_ * N_)
#define ALPHA_ 0.2f

typedef __attribute__((ext_vector_type(8))) short  short8;
typedef __attribute__((ext_vector_type(4))) float  f32x4;

__device__ __forceinline__ unsigned short f2bf(float x) {
  uint32_t u = __float_as_uint(x);
  uint32_t r = (u + 0x7fffu + ((u >> 16) & 1u)) >> 16;  // RNE
  return (unsigned short)r;
}

__device__ __forceinline__ void async_load16(const void* g, void* l) {
  __builtin_amdgcn_global_load_lds(
      (const __attribute__((address_space(1))) uint32_t*)g,
      (__attribute__((address_space(3))) uint32_t*)l, 16, 0, 0);
}

// ---------------- conversion kernels ----------------
__global__ void k_cvt_inp(const float* __restrict__ x, unsigned short* __restrict__ y) {
  int idx = (blockIdx.x * 256 + threadIdx.x) * 4;
  float4 v = *(const float4*)(x + idx);
  ushort4 p;
  p.x = f2bf(v.x); p.y = f2bf(v.y); p.z = f2bf(v.z); p.w = f2bf(v.w);
  *(ushort4*)(y + idx) = p;
}

__global__ void k_cvt_w(const float* __restrict__ W, unsigned short* __restrict__ WT) {
  int k = blockIdx.x, n = threadIdx.x;
  WT[n * F_ + k] = f2bf(W[k * F_ + n]);  // WT[f][k], k contiguous (MFMA B layout)
}

// ---------------- GEMM1: h = inp @ W, fused s1/s2, writes hT bf16 ----------------
__launch_bounds__(256, 1)
__global__ void k_gemm1(const unsigned short* __restrict__ inpb,  // [BN][F] bf16
                        const unsigned short* __restrict__ WT,    // [F][F]  bf16 (transposed W)
                        const float* __restrict__ avec,           // [2F]
                        unsigned short* __restrict__ hT,          // [F][BN] bf16
                        float* __restrict__ s1g, float* __restrict__ s2g) {
  __shared__ __align__(16) unsigned short Atile[64 * 32];   // [r][k]
  __shared__ __align__(16) unsigned short Btile[256 * 32];  // [f][k]
  __shared__ __align__(16) unsigned short Trans[256 * 72];  // [f][i], pad 64->72 (2-way only)
  __shared__ float s1_lds[64], s2_lds[64];

  const int tid  = threadIdx.x;
  const int wave = tid >> 6, lane = tid & 63;
  const int n16  = lane & 15, quad = lane >> 4;
  const int i0   = blockIdx.x * 64;

  if (tid < 64) { s1_lds[tid] = 0.0f; s2_lds[tid] = 0.0f; }

  f32x4 acc[4][4];
  #pragma unroll
  for (int mt = 0; mt < 4; ++mt)
    #pragma unroll
    for (int nt = 0; nt < 4; ++nt) acc[mt][nt] = (f32x4){0.f, 0.f, 0.f, 0.f};

  for (int k0 = 0; k0 < F_; k0 += 32) {
    {  // stage A: 1 instr/wave -> 16 rows
      int r = (wave << 4) + (lane >> 2);
      int p = lane & 3;
      async_load16(inpb + (size_t)(i0 + r) * F_ + k0 + p * 8,
                   (char*)Atile + wave * 1024);
    }
    #pragma unroll
    for (int g4 = 0; g4 < 4; ++g4) {  // stage B: 4 instr/wave -> 64 f-rows
      int f = (wave << 6) + (g4 << 4) + (lane >> 2);
      int p = lane & 3;
      async_load16(WT + (size_t)f * F_ + k0 + p * 8,
                   (char*)Btile + wave * 4096 + g4 * 1024);
    }
    __syncthreads();

    short8 af[4], bf_[4];
    #pragma unroll
    for (int mt = 0; mt < 4; ++mt)
      af[mt] = *(const short8*)((const char*)Atile + ((mt * 16 + n16) * 64 + quad * 16));
    #pragma unroll
    for (int nt = 0; nt < 4; ++nt)
      bf_[nt] = *(const short8*)((const char*)Btile + ((wave * 64 + nt * 16 + n16) * 64 + quad * 16));
    #pragma unroll
    for (int mt = 0; mt < 4; ++mt)
      #pragma unroll
      for (int nt = 0; nt < 4; ++nt)
        acc[mt][nt] = __builtin_amdgcn_mfma_f32_16x16x32_bf16(af[mt], bf_[nt], acc[mt][nt], 0, 0, 0);
    __syncthreads();
  }

  // ---- epilogue ----
  // 1) C-tile -> LDS transpose buffer [f][i]
  #pragma unroll
  for (int mt = 0; mt < 4; ++mt)
    #pragma unroll
    for (int nt = 0; nt < 4; ++nt) {
      int f = (wave << 6) + (nt << 4) + n16;
      int i = (mt << 4) + (quad << 2);
      ushort4 pk;
      pk.x = f2bf(acc[mt][nt][0]); pk.y = f2bf(acc[mt][nt][1]);
      pk.z = f2bf(acc[mt][nt][2]); pk.w = f2bf(acc[mt][nt][3]);
      *(ushort4*)(Trans + f * 72 + i) = pk;
    }

  // 2) fused s1/s2 (from f32 accumulators)
  float a1v[4], a2v[4];
  #pragma unroll
  for (int nt = 0; nt < 4; ++nt) {
    int f = (wave << 6) + (nt << 4) + n16;
    a1v[nt] = avec[f];
    a2v[nt] = avec[F_ + f];
  }
  #pragma unroll
  for (int mt = 0; mt < 4; ++mt) {
    float s1p[4] = {0, 0, 0, 0}, s2p[4] = {0, 0, 0, 0};
    #pragma unroll
    for (int nt = 0; nt < 4; ++nt)
      #pragma unroll
      for (int rg = 0; rg < 4; ++rg) {
        s1p[rg] = fmaf(acc[mt][nt][rg], a1v[nt], s1p[rg]);
        s2p[rg] = fmaf(acc[mt][nt][rg], a2v[nt], s2p[rg]);
      }
    #pragma unroll
    for (int rg = 0; rg < 4; ++rg) {
      float v1 = s1p[rg], v2 = s2p[rg];
      #pragma unroll
      for (int off = 1; off < 16; off <<= 1) {
        v1 += __shfl_xor(v1, off);
        v2 += __shfl_xor(v2, off);
      }
      if (n16 == 0) {
        atomicAdd(&s1_lds[(mt << 4) + (quad << 2) + rg], v1);
        atomicAdd(&s2_lds[(mt << 4) + (quad << 2) + rg], v2);
      }
    }
  }
  __syncthreads();

  // 3) coalesced hT store: 8 lanes x 16 B = 128 B contiguous per f-row
  #pragma unroll
  for (int it = 0; it < 8; ++it) {
    int f = it * 32 + wave * 8 + (lane >> 3);
    int i = (lane & 7) * 8;
    short8 v = *(const short8*)(Trans + f * 72 + i);
    *(short8*)(hT + (size_t)f * BN_ + i0 + i) = v;
  }
  if (tid < 64) {
    s1g[i0 + tid] = s1_lds[tid];
    s2g[i0 + tid] = s2_lds[tid];
  }
}

// ---------------- per-batch min/max of s1/s2 -> affine params ----------------
__global__ void k_minmax(const float* __restrict__ s1, const float* __restrict__ s2,
                         float2* __restrict__ params) {
  int b = blockIdx.x, tid = threadIdx.x;
  float mn1 = 1e30f, mx1 = -1e30f, mn2 = 1e30f, mx2 = -1e30f;
  for (int i = tid; i < N_; i += 256) {
    float v1 = s1[b * N_ + i]; mn1 = fminf(mn1, v1); mx1 = fmaxf(mx1, v1);
    float v2 = s2[b * N_ + i]; mn2 = fminf(mn2, v2); mx2 = fmaxf(mx2, v2);
  }
  #pragma unroll
  for (int off = 1; off < 64; off <<= 1) {
    mn1 = fminf(mn1, __shfl_xor(mn1, off));
    mx1 = fmaxf(mx1, __shfl_xor(mx1, off));
    mn2 = fminf(mn2, __shfl_xor(mn2, off));
    mx2 = fmaxf(mx2, __shfl_xor(mx2, off));
  }
  __shared__ float red[4][4];
  int wave = tid >> 6, lane = tid & 63;
  if (lane == 0) { red[wave][0] = mn1; red[wave][1] = mx1; red[wave][2] = mn2; red[wave][3] = mx2; }
  __syncthreads();
  if (tid == 0) {
    for (int w = 1; w < 4; ++w) {
      mn1 = fminf(mn1, red[w][0]); mx1 = fmaxf(mx1, red[w][1]);
      mn2 = fminf(mn2, red[w][2]); mx2 = fmaxf(mx2, red[w][3]);
    }
    // leaky_relu monotone: extremes of e come from extremes of s1+s2
    float smn = mn1 + mn2, smx = mx1 + mx2;
    float mn = fmaxf(smn, ALPHA_ * smn);
    float mx = fmaxf(smx, ALPHA_ * smx);
    float scale = 30.0f / (mx - mn);
    float bias  = -mn * scale - 20.0f;
    params[b] = make_float2(-scale, -bias);  // for u = -e: att = rcp(1+exp(u))
  }
}

// ---------------- GEMM2: 32-row tiles, 512 blocks (2 blocks/CU) ----------------
__launch_bounds__(256, 2)
__global__ void k_gemm2(const unsigned short* __restrict__ hT,  // [F][BN] bf16
                        const float* __restrict__ s1, const float* __restrict__ s2,
                        const float2* __restrict__ params,
                        float* __restrict__ hprime,  // [B][N][F]
                        float* __restrict__ att) {   // [B][N][N]
  __shared__ __align__(16) unsigned short Atile[32 * 32];   // attention tile [r][k]
  __shared__ __align__(16) unsigned short Btile[256 * 32];  // hT tile [f][k]

  const int tid  = threadIdx.x;
  const int wave = tid >> 6, lane = tid & 63;
  const int n16  = lane & 15, quad = lane >> 4;
  const int blk  = blockIdx.x;
  const int b    = blk & 7;            // batch = blk%8 -> XCD-local hT_b in L2
  const int i0   = (blk >> 3) * 32;    // 32-row tile within batch

  const float2 pb = params[b];
  const float uscale = pb.x, ubias = pb.y;

  const int r_att = tid >> 3;   // 0..31
  const int c_att = tid & 7;    // j-chunk of 4
  const float s1v = s1[b * N_ + i0 + r_att];
  const float* s2b = s2 + b * N_;
  float* attrow = att + ((size_t)(b * N_ + i0 + r_att)) * N_;

  f32x4 acc[2][4];
  #pragma unroll
  for (int mt = 0; mt < 2; ++mt)
    #pragma unroll
    for (int nt = 0; nt < 4; ++nt) acc[mt][nt] = (f32x4){0.f, 0.f, 0.f, 0.f};

  for (int k0 = 0; k0 < N_; k0 += 32) {
    #pragma unroll
    for (int g4 = 0; g4 < 4; ++g4) {  // stage hT tile (256 f-rows x 32 k)
      int f = (wave << 6) + (g4 << 4) + (lane >> 2);
      int p = lane & 3;
      async_load16(hT + (size_t)f * BN_ + b * N_ + k0 + p * 8,
                   (char*)Btile + wave * 4096 + g4 * 1024);
    }

    // 4 attention values/thread (overlaps with async staging)
    float4 va = *(const float4*)(s2b + k0 + c_att * 4);
    float v[4] = {va.x, va.y, va.z, va.w};
    ushort4 spk;
    #pragma unroll
    for (int jj = 0; jj < 4; ++jj) {
      float s = s1v + v[jj];
      float l = fmaxf(s, ALPHA_ * s);                       // leaky_relu
      float u = fmaf(l, uscale, ubias);                     // u = -e_norm
      float p_ = __builtin_amdgcn_rcpf(1.0f + __expf(u));   // sigmoid(e_norm)
      v[jj] = p_;
    }
    spk.x = f2bf(v[0]); spk.y = f2bf(v[1]); spk.z = f2bf(v[2]); spk.w = f2bf(v[3]);
    // coalesced: 8 lanes x 16 B = 128 B contiguous per att row
    *(float4*)(attrow + k0 + c_att * 4) = make_float4(v[0], v[1], v[2], v[3]);
    *(ushort4*)(Atile + tid * 4) = spk;   // [r_att][c_att*4] == tid*4
    __syncthreads();

    short8 af[2], bf_[4];
    #pragma unroll
    for (int mt = 0; mt < 2; ++mt)
      af[mt] = *(const short8*)((const char*)Atile + ((mt * 16 + n16) * 64 + quad * 16));
    #pragma unroll
    for (int nt = 0; nt < 4; ++nt)
      bf_[nt] = *(const short8*)((const char*)Btile + ((wave * 64 + nt * 16 + n16) * 64 + quad * 16));
    #pragma unroll
    for (int mt = 0; mt < 2; ++mt)
      #pragma unroll
      for (int nt = 0; nt < 4; ++nt)
        acc[mt][nt] = __builtin_amdgcn_mfma_f32_16x16x32_bf16(af[mt], bf_[nt], acc[mt][nt], 0, 0, 0);
    __syncthreads();
  }

  // epilogue: ELU + store h_prime
  float* hp = hprime + ((size_t)(b * N_ + i0)) * F_;
  #pragma unroll
  for (int mt = 0; mt < 2; ++mt)
    #pragma unroll
    for (int nt = 0; nt < 4; ++nt) {
      int fcol = (wave << 6) + (nt << 4) + n16;
      int irow = (mt << 4) + (quad << 2);
      #pragma unroll
      for (int rg = 0; rg < 4; ++rg) {
        float x = acc[mt][nt][rg];
        float y = x > 0.0f ? x : (__expf(x) - 1.0f);
        hp[(size_t)(irow + rg) * F_ + fcol] = y;
      }
    }
}

// ---------------- launch ----------------
extern "C" void kernel_launch(void* const* d_in, const int* in_sizes, int n_in,
                              void* d_out, int out_size, void* d_ws, size_t ws_size,
                              hipStream_t stream) {
  const float* inp  = (const float*)d_in[0];
  // d_in[1] = adj: unused by the reference computation
  const float* W    = (const float*)d_in[2];
  const float* avec = (const float*)d_in[3];

  float* hprime = (float*)d_out;                         // [8][2048][256]
  float* att    = (float*)d_out + (size_t)B_ * N_ * F_;  // [8][2048][2048]

  char* ws = (char*)d_ws;
  unsigned short* inpb = (unsigned short*)ws;                          // 8 MB
  unsigned short* WT   = (unsigned short*)(ws + 8388608);              // 128 KB
  unsigned short* hT   = (unsigned short*)(ws + 8388608 + 131072);     // 8 MB
  float* s1            = (float*)(ws + 8388608 + 131072 + 8388608);
  float* s2            = s1 + BN_;
  float2* params       = (float2*)(s2 + BN_);

  k_cvt_inp<<<(BN_ * F_) / 1024, 256, 0, stream>>>(inp, inpb);
  k_cvt_w<<<F_, F_, 0, stream>>>(W, WT);
  k_gemm1<<<BN_ / 64, 256, 0, stream>>>(inpb, WT, avec, hT, s1, s2);
  k_minmax<<<B_, 256, 0, stream>>>(s1, s2, params);
  k_gemm2<<<512, 256, 0, stream>>>(hT, s1, s2, params, hprime, att);
}

// Round 4
// 281.552 us; speedup vs baseline: 1.0948x; 1.0275x over previous
//
#include <hip/hip_runtime.h>
#include <stdint.h>

#define B_   8
#define N_   2048
#define F_   256
#define BN_  (B_ * N_)
#define ALPHA_ 0.2f

typedef __attribute__((ext_vector_type(8))) short  short8;
typedef __attribute__((ext_vector_type(4))) float  f32x4;

__device__ __forceinline__ unsigned short f2bf(float x) {
  uint32_t u = __float_as_uint(x);
  uint32_t r = (u + 0x7fffu + ((u >> 16) & 1u)) >> 16;  // RNE
  return (unsigned short)r;
}

// monotone float -> uint key (order-preserving), and inverse
__device__ __forceinline__ uint32_t fkey(float f) {
  uint32_t b = __float_as_uint(f);
  return b ^ (uint32_t)(((int32_t)b >> 31) | (int32_t)0x80000000);
}
__device__ __forceinline__ float ikey(uint32_t k) {
  uint32_t b = (k & 0x80000000u) ? (k ^ 0x80000000u) : ~k;
  return __uint_as_float(b);
}

__device__ __forceinline__ void async_load16(const void* g, void* l) {
  __builtin_amdgcn_global_load_lds(
      (const __attribute__((address_space(1))) uint32_t*)g,
      (__attribute__((address_space(3))) uint32_t*)l, 16, 0, 0);
}

// nontemporal 16B store (builtin requires ext_vector_type, not HIP float4)
__device__ __forceinline__ void nt_store4(float* p, f32x4 v) {
  __builtin_nontemporal_store(v, (f32x4*)p);
}

// ---------------- W transpose to bf16 [f][k] ----------------
__global__ void k_cvt_w(const float* __restrict__ W, unsigned short* __restrict__ WT) {
  int k = blockIdx.x, n = threadIdx.x;
  WT[n * F_ + k] = f2bf(W[k * F_ + n]);  // WT[f][k], k contiguous (MFMA B layout)
}

// ---------------- GEMM1: h = inp @ W (inp f32 converted in-register),
//                  fused s1/s2 + per-batch min/max atomics, writes hT bf16 ----------------
__launch_bounds__(256, 1)
__global__ void k_gemm1(const float* __restrict__ inp,            // [BN][F] f32
                        const unsigned short* __restrict__ WT,    // [F][F]  bf16 (transposed W)
                        const float* __restrict__ avec,           // [2F]
                        unsigned short* __restrict__ hT,          // [F][BN] bf16
                        float* __restrict__ s1g, float* __restrict__ s2g,
                        uint32_t* __restrict__ maxk, uint32_t* __restrict__ mink) {
  __shared__ __align__(16) unsigned short Atile[64 * 32];   // [r][k]
  __shared__ __align__(16) unsigned short Btile[256 * 32];  // [f][k]
  __shared__ __align__(16) unsigned short Trans[256 * 72];  // [f][i], pad 64->72
  __shared__ float s1_lds[64], s2_lds[64];

  const int tid  = threadIdx.x;
  const int wave = tid >> 6, lane = tid & 63;
  const int n16  = lane & 15, quad = lane >> 4;
  const int i0   = blockIdx.x * 64;
  const int b    = i0 >> 11;  // batch (2048 rows each; 64 | 2048)

  if (tid < 64) { s1_lds[tid] = 0.0f; s2_lds[tid] = 0.0f; }

  f32x4 acc[4][4];
  #pragma unroll
  for (int mt = 0; mt < 4; ++mt)
    #pragma unroll
    for (int nt = 0; nt < 4; ++nt) acc[mt][nt] = (f32x4){0.f, 0.f, 0.f, 0.f};

  for (int k0 = 0; k0 < F_; k0 += 32) {
    {  // stage A from f32 inp: convert in-register, ds_write_b128
      int r = tid >> 2, cp = tid & 3;
      const float* gp = inp + (size_t)(i0 + r) * F_ + k0 + cp * 8;
      float4 va = *(const float4*)gp;
      float4 vb = *(const float4*)(gp + 4);
      short8 sv;
      sv[0] = (short)f2bf(va.x); sv[1] = (short)f2bf(va.y);
      sv[2] = (short)f2bf(va.z); sv[3] = (short)f2bf(va.w);
      sv[4] = (short)f2bf(vb.x); sv[5] = (short)f2bf(vb.y);
      sv[6] = (short)f2bf(vb.z); sv[7] = (short)f2bf(vb.w);
      *(short8*)((char*)Atile + r * 64 + cp * 16) = sv;
    }
    #pragma unroll
    for (int g4 = 0; g4 < 4; ++g4) {  // stage B (bf16 WT): 4 instr/wave
      int f = (wave << 6) + (g4 << 4) + (lane >> 2);
      int p = lane & 3;
      async_load16(WT + (size_t)f * F_ + k0 + p * 8,
                   (char*)Btile + wave * 4096 + g4 * 1024);
    }
    __syncthreads();

    short8 af[4], bf_[4];
    #pragma unroll
    for (int mt = 0; mt < 4; ++mt)
      af[mt] = *(const short8*)((const char*)Atile + ((mt * 16 + n16) * 64 + quad * 16));
    #pragma unroll
    for (int nt = 0; nt < 4; ++nt)
      bf_[nt] = *(const short8*)((const char*)Btile + ((wave * 64 + nt * 16 + n16) * 64 + quad * 16));
    #pragma unroll
    for (int mt = 0; mt < 4; ++mt)
      #pragma unroll
      for (int nt = 0; nt < 4; ++nt)
        acc[mt][nt] = __builtin_amdgcn_mfma_f32_16x16x32_bf16(af[mt], bf_[nt], acc[mt][nt], 0, 0, 0);
    __syncthreads();
  }

  // ---- epilogue ----
  // 1) C-tile -> LDS transpose buffer [f][i]
  #pragma unroll
  for (int mt = 0; mt < 4; ++mt)
    #pragma unroll
    for (int nt = 0; nt < 4; ++nt) {
      int f = (wave << 6) + (nt << 4) + n16;
      int i = (mt << 4) + (quad << 2);
      ushort4 pk;
      pk.x = f2bf(acc[mt][nt][0]); pk.y = f2bf(acc[mt][nt][1]);
      pk.z = f2bf(acc[mt][nt][2]); pk.w = f2bf(acc[mt][nt][3]);
      *(ushort4*)(Trans + f * 72 + i) = pk;
    }

  // 2) fused s1/s2 from f32 accumulators
  float a1v[4], a2v[4];
  #pragma unroll
  for (int nt = 0; nt < 4; ++nt) {
    int f = (wave << 6) + (nt << 4) + n16;
    a1v[nt] = avec[f];
    a2v[nt] = avec[F_ + f];
  }
  #pragma unroll
  for (int mt = 0; mt < 4; ++mt) {
    float s1p[4] = {0, 0, 0, 0}, s2p[4] = {0, 0, 0, 0};
    #pragma unroll
    for (int nt = 0; nt < 4; ++nt)
      #pragma unroll
      for (int rg = 0; rg < 4; ++rg) {
        s1p[rg] = fmaf(acc[mt][nt][rg], a1v[nt], s1p[rg]);
        s2p[rg] = fmaf(acc[mt][nt][rg], a2v[nt], s2p[rg]);
      }
    #pragma unroll
    for (int rg = 0; rg < 4; ++rg) {
      float v1 = s1p[rg], v2 = s2p[rg];
      #pragma unroll
      for (int off = 1; off < 16; off <<= 1) {
        v1 += __shfl_xor(v1, off);
        v2 += __shfl_xor(v2, off);
      }
      if (n16 == 0) {
        atomicAdd(&s1_lds[(mt << 4) + (quad << 2) + rg], v1);
        atomicAdd(&s2_lds[(mt << 4) + (quad << 2) + rg], v2);
      }
    }
  }
  __syncthreads();

  // 3) coalesced hT store: 8 lanes x 16 B = 128 B contiguous per f-row
  #pragma unroll
  for (int it = 0; it < 8; ++it) {
    int f = it * 32 + wave * 8 + (lane >> 3);
    int i = (lane & 7) * 8;
    short8 v = *(const short8*)(Trans + f * 72 + i);
    *(short8*)(hT + (size_t)f * BN_ + i0 + i) = v;
  }

  // 4) s1/s2 store + block min/max -> keyed global atomics (wave 0 only)
  if (tid < 64) {
    float v1 = s1_lds[tid], v2 = s2_lds[tid];
    s1g[i0 + tid] = v1;
    s2g[i0 + tid] = v2;
    float mn1 = v1, mx1 = v1, mn2 = v2, mx2 = v2;
    #pragma unroll
    for (int off = 1; off < 64; off <<= 1) {
      mn1 = fminf(mn1, __shfl_xor(mn1, off));
      mx1 = fmaxf(mx1, __shfl_xor(mx1, off));
      mn2 = fminf(mn2, __shfl_xor(mn2, off));
      mx2 = fmaxf(mx2, __shfl_xor(mx2, off));
    }
    if (tid == 0) {
      atomicMax(&maxk[b * 2 + 0], fkey(mx1));
      atomicMax(&maxk[b * 2 + 1], fkey(mx2));
      atomicMin(&mink[b * 2 + 0], fkey(mn1));
      atomicMin(&mink[b * 2 + 1], fkey(mn2));
    }
  }
}

// ---------------- GEMM2: params from keys; att on the fly; h_prime = elu(att @ h) ----------------
__launch_bounds__(256, 2)
__global__ void k_gemm2(const unsigned short* __restrict__ hT,  // [F][BN] bf16
                        const float* __restrict__ s1, const float* __restrict__ s2,
                        const uint32_t* __restrict__ maxk, const uint32_t* __restrict__ mink,
                        float* __restrict__ hprime,  // [B][N][F]
                        float* __restrict__ att) {   // [B][N][N]
  __shared__ __align__(16) unsigned short Atile[32 * 32];   // attention tile [r][k]
  __shared__ __align__(16) unsigned short Btile[256 * 32];  // hT tile [f][k]

  const int tid  = threadIdx.x;
  const int wave = tid >> 6, lane = tid & 63;
  const int n16  = lane & 15, quad = lane >> 4;
  const int blk  = blockIdx.x;
  const int b    = blk & 7;            // batch = blk%8 -> XCD-local hT_b in L2
  const int i0   = (blk >> 3) * 32;    // 32-row tile within batch

  // normalization params (leaky_relu monotone => extremes from extremes of s1+s2)
  float mx1 = ikey(maxk[b * 2 + 0]), mx2 = ikey(maxk[b * 2 + 1]);
  float mn1 = ikey(mink[b * 2 + 0]), mn2 = ikey(mink[b * 2 + 1]);
  float smn = mn1 + mn2, smx = mx1 + mx2;
  float emn = fmaxf(smn, ALPHA_ * smn);
  float emx = fmaxf(smx, ALPHA_ * smx);
  float scale  = 30.0f / (emx - emn);
  const float uscale = -scale;                 // u = -e_norm
  const float ubias  = emn * scale + 20.0f;

  const int r_att = tid >> 3;   // 0..31
  const int c_att = tid & 7;    // j-chunk of 4
  const float s1v = s1[b * N_ + i0 + r_att];
  const float* s2b = s2 + b * N_;
  float* attrow = att + ((size_t)(b * N_ + i0 + r_att)) * N_;

  f32x4 acc[2][4];
  #pragma unroll
  for (int mt = 0; mt < 2; ++mt)
    #pragma unroll
    for (int nt = 0; nt < 4; ++nt) acc[mt][nt] = (f32x4){0.f, 0.f, 0.f, 0.f};

  for (int k0 = 0; k0 < N_; k0 += 32) {
    #pragma unroll
    for (int g4 = 0; g4 < 4; ++g4) {  // stage hT tile (256 f-rows x 32 k)
      int f = (wave << 6) + (g4 << 4) + (lane >> 2);
      int p = lane & 3;
      async_load16(hT + (size_t)f * BN_ + b * N_ + k0 + p * 8,
                   (char*)Btile + wave * 4096 + g4 * 1024);
    }

    // 4 attention values/thread (overlaps with async staging)
    float4 va = *(const float4*)(s2b + k0 + c_att * 4);
    float v[4] = {va.x, va.y, va.z, va.w};
    ushort4 spk;
    #pragma unroll
    for (int jj = 0; jj < 4; ++jj) {
      float s = s1v + v[jj];
      float l = fmaxf(s, ALPHA_ * s);                       // leaky_relu
      float u = fmaf(l, uscale, ubias);                     // u = -e_norm
      float p_ = __builtin_amdgcn_rcpf(1.0f + __expf(u));   // sigmoid(e_norm)
      v[jj] = p_;
    }
    spk.x = f2bf(v[0]); spk.y = f2bf(v[1]); spk.z = f2bf(v[2]); spk.w = f2bf(v[3]);
    // nontemporal: att is write-once, keep it out of L2 (hT tiles live there)
    nt_store4(attrow + k0 + c_att * 4, (f32x4){v[0], v[1], v[2], v[3]});
    *(ushort4*)(Atile + tid * 4) = spk;   // [r_att][c_att*4] == tid*4
    __syncthreads();

    short8 af[2], bf_[4];
    #pragma unroll
    for (int mt = 0; mt < 2; ++mt)
      af[mt] = *(const short8*)((const char*)Atile + ((mt * 16 + n16) * 64 + quad * 16));
    #pragma unroll
    for (int nt = 0; nt < 4; ++nt)
      bf_[nt] = *(const short8*)((const char*)Btile + ((wave * 64 + nt * 16 + n16) * 64 + quad * 16));
    #pragma unroll
    for (int mt = 0; mt < 2; ++mt)
      #pragma unroll
      for (int nt = 0; nt < 4; ++nt)
        acc[mt][nt] = __builtin_amdgcn_mfma_f32_16x16x32_bf16(af[mt], bf_[nt], acc[mt][nt], 0, 0, 0);
    __syncthreads();
  }

  // epilogue: ELU + nontemporal store h_prime
  float* hp = hprime + ((size_t)(b * N_ + i0)) * F_;
  #pragma unroll
  for (int mt = 0; mt < 2; ++mt)
    #pragma unroll
    for (int nt = 0; nt < 4; ++nt) {
      int fcol = (wave << 6) + (nt << 4) + n16;
      int irow = (mt << 4) + (quad << 2);
      #pragma unroll
      for (int rg = 0; rg < 4; ++rg) {
        float x = acc[mt][nt][rg];
        float y = x > 0.0f ? x : (__expf(x) - 1.0f);
        __builtin_nontemporal_store(y, hp + (size_t)(irow + rg) * F_ + fcol);
      }
    }
}

// ---------------- launch ----------------
extern "C" void kernel_launch(void* const* d_in, const int* in_sizes, int n_in,
                              void* d_out, int out_size, void* d_ws, size_t ws_size,
                              hipStream_t stream) {
  const float* inp  = (const float*)d_in[0];
  // d_in[1] = adj: unused by the reference computation
  const float* W    = (const float*)d_in[2];
  const float* avec = (const float*)d_in[3];

  float* hprime = (float*)d_out;                         // [8][2048][256]
  float* att    = (float*)d_out + (size_t)B_ * N_ * F_;  // [8][2048][2048]

  char* ws = (char*)d_ws;
  unsigned short* WT = (unsigned short*)ws;                           // 128 KB
  unsigned short* hT = (unsigned short*)(ws + 131072);                // 8 MB
  float* s1          = (float*)(ws + 131072 + 8388608);               // 64 KB
  float* s2          = s1 + BN_;                                      // 64 KB
  uint32_t* maxk     = (uint32_t*)(s2 + BN_);                         // 16 u32
  uint32_t* mink     = maxk + 16;                                     // 16 u32

  (void)hipMemsetAsync(maxk, 0x00, 64, stream);   // fkey-min init for atomicMax
  (void)hipMemsetAsync(mink, 0xFF, 64, stream);   // fkey-max init for atomicMin

  k_cvt_w<<<F_, F_, 0, stream>>>(W, WT);
  k_gemm1<<<BN_ / 64, 256, 0, stream>>>(inp, WT, avec, hT, s1, s2, maxk, mink);
  k_gemm2<<<512, 256, 0, stream>>>(hT, s1, s2, maxk, mink, hprime, att);
}